// Round 3
// baseline (592.511 us; speedup 1.0000x reference)
//
#include <hip/hip_runtime.h>
#include <math.h>
#include <stdint.h>

#define G_ZERO 0.5f

typedef _Float16 half8 __attribute__((ext_vector_type(8)));
typedef float f32x4 __attribute__((ext_vector_type(4)));

// ---------------------------------------------------------------------------
// Weight repack: w fp32 [128][C][3][3] -> f16 hi/lo, linear layout
//   dst halfword = tt*4096 + oc*32 + kloc     (tt = (ky*3+kx)*nCs + cs)
// so one wave's B-fragment loads (lane ln15 -> oc, g16 -> k-block) are a
// contiguous, perfectly coalesced 1KB dwordx4 read straight from L1/L2.
// ---------------------------------------------------------------------------
template<int C>
__global__ __launch_bounds__(256)
void repack_w(const float* __restrict__ w, uint16_t* __restrict__ whi,
              uint16_t* __restrict__ wlo)
{
    constexpr int nCs = C / 32;
    constexpr int nCh = 9 * nCs;
    int idx = blockIdx.x * 256 + threadIdx.x;
    if (idx >= nCh * 128 * 32) return;
    int kloc = idx & 31;
    int oc   = (idx >> 5) & 127;
    int tt   = idx >> 12;
    int kyx = tt / nCs, cs = tt % nCs;
    int ky = kyx / 3, kx = kyx % 3;
    int c = cs * 32 + kloc;
    float v = w[(size_t)oc * C * 9 + c * 9 + ky * 3 + kx];
    _Float16 hi = (_Float16)v;
    _Float16 lo = (_Float16)(v - (float)hi);
    int dst = tt * 4096 + oc * 32 + kloc;
    whi[dst] = __builtin_bit_cast(uint16_t, hi);
    wlo[dst] = __builtin_bit_cast(uint16_t, lo);
}

// ---------------------------------------------------------------------------
// Implicit-GEMM conv3x3, mfma_f32_16x16x32_f16, 3-pass hi/lo split with
// pass-sharing: per K-chunk read Ah/Al (LDS) + Bh/Bl (global, L1-resident)
// once and issue all 48 MFMAs. A tile staged ONCE per block; the unrolled
// K-loop has no barriers. A addressing: 6 precomputed per-lane column terms,
// per-read = 1 xor (compile-time const) + 1 add; row -> ds offset imm.
// ---------------------------------------------------------------------------
template<int C, bool NHWC_IN>
__global__ __launch_bounds__(256, 3)
void conv_mfma(const float* __restrict__ in, const uint16_t* __restrict__ whi,
               const uint16_t* __restrict__ wlo, const float* __restrict__ bias,
               float* __restrict__ gh)
{
    constexpr int nCs = C / 32;
    constexpr int CB = 2 * C;                  // f16 channels incl. lo plane
    constexpr int CMASK = CB / 8 - 1;          // xor swizzle over 16B blocks
    constexpr int PIX_B = CB * 2;              // bytes per pixel in A tile

    __shared__ char smem[6 * 34 * PIX_B];

    const int tid = threadIdx.x;
    const int l = tid & 63;
    const int wv = tid >> 6;
    const int wv_m = wv >> 1, wv_n = wv & 1;
    const int g16 = l >> 4;
    const int ln15 = l & 15;
    const int img = blockIdx.x >> 3;
    const int y0 = (blockIdx.x & 7) * 4;

    // ---- zero halo columns 0 and 33 (both planes)
    for (int e = tid; e < 6 * 2 * (PIX_B / 4); e += 256) {
        int pj = e / (PIX_B / 4);
        int j  = e % (PIX_B / 4);
        int row = pj >> 1;
        int col = (pj & 1) ? 33 : 0;
        *(float*)(smem + (row * 34 + col) * PIX_B + j * 4) = 0.f;
    }
    // ---- stage A tile once: rows y0-1..y0+4, cols 1..32, hi+lo planes
    for (int e = tid; e < C * 192; e += 256) {
        int c, x, y6;
        if constexpr (NHWC_IN) { c = e & (C - 1); int r2 = e >> 6; x = r2 & 31; y6 = r2 >> 5; }
        else                   { x = e & 31; int r2 = e >> 5; y6 = r2 % 6; c = r2 / 6; }
        int gy = y0 - 1 + y6;
        float v = 0.f;
        if ((unsigned)gy < 32u) {
            if constexpr (NHWC_IN) v = in[((size_t)img * 1024 + gy * 32 + x) * C + c];
            else                   v = in[((size_t)img * C + c) * 1024 + gy * 32 + x];
        }
        _Float16 hi = (_Float16)v;
        _Float16 lo = (_Float16)(v - (float)hi);
        int col = x + 1;
        int slot = (c >> 3) ^ (col & CMASK);
        int addr = (y6 * 34 + col) * PIX_B + slot * 16 + (c & 7) * 2;
        *(uint16_t*)(smem + addr) = __builtin_bit_cast(uint16_t, hi);
        *(uint16_t*)(smem + (addr ^ (2 * C))) = __builtin_bit_cast(uint16_t, lo);
    }
    __syncthreads();   // only barrier in the kernel

    // ---- per-lane precomputed A column terms: col*PIX_B + (((col&CMASK)^g16)<<4)
    int acol[3][2];
    #pragma unroll
    for (int kx = 0; kx < 3; ++kx)
        #pragma unroll
        for (int m1 = 0; m1 < 2; ++m1) {
            int col = m1 * 16 + ln15 + kx;
            acol[kx][m1] = col * PIX_B + (((col & CMASK) ^ g16) << 4);
        }
    const int rowbase = wv_m * 2 * 34 * PIX_B;
    const char* wbh = (const char*)whi + (wv_n * 64 + ln15) * 64 + g16 * 16;
    const char* wbl = (const char*)wlo + (wv_n * 64 + ln15) * 64 + g16 * 16;

    f32x4 acc[4][4];
    #pragma unroll
    for (int mf = 0; mf < 4; ++mf)
        #pragma unroll
        for (int nf = 0; nf < 4; ++nf) acc[mf][nf] = (f32x4)0.f;

    #pragma unroll
    for (int ky = 0; ky < 3; ++ky)
    #pragma unroll
    for (int kx = 0; kx < 3; ++kx)
    #pragma unroll
    for (int cs = 0; cs < nCs; ++cs) {
        const int tt = (ky * 3 + kx) * nCs + cs;

        half8 bh[4], bl[4];
        #pragma unroll
        for (int nf = 0; nf < 4; ++nf) {
            bh[nf] = *(const half8*)(wbh + tt * 8192 + nf * 1024);
            bl[nf] = *(const half8*)(wbl + tt * 8192 + nf * 1024);
        }
        half8 ah[4], al[4];
        #pragma unroll
        for (int mf = 0; mf < 4; ++mf) {
            const int m1 = mf & 1;
            const int imm = ((mf >> 1) + ky) * 34 * PIX_B;   // compile-time
            const int XH = (cs * 4) << 4;                    // compile-time
            const int XL = (C / 8 + cs * 4) << 4;            // compile-time
            ah[mf] = *(const half8*)(smem + rowbase + (acol[kx][m1] ^ XH) + imm);
            al[mf] = *(const half8*)(smem + rowbase + (acol[kx][m1] ^ XL) + imm);
        }
        #pragma unroll
        for (int mf = 0; mf < 4; ++mf)
            #pragma unroll
            for (int nf = 0; nf < 4; ++nf)
                acc[mf][nf] = __builtin_amdgcn_mfma_f32_16x16x32_f16(
                    ah[mf], bh[nf], acc[mf][nf], 0, 0, 0);
        #pragma unroll
        for (int mf = 0; mf < 4; ++mf)
            #pragma unroll
            for (int nf = 0; nf < 4; ++nf)
                acc[mf][nf] = __builtin_amdgcn_mfma_f32_16x16x32_f16(
                    ah[mf], bl[nf], acc[mf][nf], 0, 0, 0);
        #pragma unroll
        for (int mf = 0; mf < 4; ++mf)
            #pragma unroll
            for (int nf = 0; nf < 4; ++nf)
                acc[mf][nf] = __builtin_amdgcn_mfma_f32_16x16x32_f16(
                    al[mf], bh[nf], acc[mf][nf], 0, 0, 0);
    }

    // ---- epilogue: C/D layout col(oc)=lane&15, row(px)=(lane>>4)*4+reg (m89)
    #pragma unroll
    for (int mf = 0; mf < 4; ++mf) {
        int pbase = wv_m * 64 + mf * 16 + g16 * 4;
        #pragma unroll
        for (int nf = 0; nf < 4; ++nf) {
            int oc = wv_n * 64 + nf * 16 + ln15;
            float bv = bias[oc];
            #pragma unroll
            for (int r = 0; r < 4; ++r) {
                int pp = pbase + r;
                int y = y0 + (pp >> 5), x = pp & 31;
                gh[((size_t)img * 1024 + y * 32 + x) * 128 + oc] = acc[mf][nf][r] + bv;
            }
        }
    }
}

// ---------------------------------------------------------------------------
// scan1: gh NHWC [img][1024][128] -> out1 NHWC [img][1024][64], h1 NCHW.
// ---------------------------------------------------------------------------
__global__ __launch_bounds__(256)
void scan_nhwc(const float* __restrict__ gh, float* __restrict__ out1,
               float* __restrict__ h1)
{
    int idx = blockIdx.x * 256 + threadIdx.x;   // 262144 total
    int cg = idx & 63;
    int hw = (idx >> 6) & 1023;
    int b  = idx >> 16;
    const float* gp = gh + ((size_t)(b * 64) * 1024 + hw) * 128 + cg;
    float* op = out1 + ((size_t)(b * 64) * 1024 + hw) * 64 + cg;
    float h = G_ZERO;
    for (int s = 0; s < 64; ++s) {
        float gate = gp[(size_t)s * 131072];
        float hid  = gp[(size_t)s * 131072 + 64];
        float z  = 1.f / (1.f + __expf(-gate));
        float gv = (hid >= 0.f) ? hid + 0.5f : 1.f / (1.f + __expf(-hid));
        h = (1.f - z) * h + z * gv;
        op[(size_t)s * 65536] = h;
    }
    h1[(size_t)(b * 64 + cg) * 1024 + hw] = h;
}

// ---------------------------------------------------------------------------
// scan2: gh NHWC -> out2 NCHW + h2 NCHW, LDS bounce for the transpose.
// ---------------------------------------------------------------------------
__global__ __launch_bounds__(256)
void scan_nchw(const float* __restrict__ gh, float* __restrict__ out2,
               float* __restrict__ h2)
{
    __shared__ float sh2[16][65];
    int tid = threadIdx.x;
    int b   = blockIdx.x >> 6;
    int hw0 = (blockIdx.x & 63) * 16;
    int cg = tid & 63, pq = tid >> 6;          // compute mapping (cg fastest)
    int opx = tid & 15, ocq = tid >> 4;        // store mapping (px fastest)
    float h[4] = {G_ZERO, G_ZERO, G_ZERO, G_ZERO};
    for (int s = 0; s < 64; ++s) {
        size_t ib = (size_t)(b * 64 + s) * 1024 + hw0;
        #pragma unroll
        for (int i = 0; i < 4; ++i) {
            int px = pq * 4 + i;
            float gate = gh[(ib + px) * 128 + cg];
            float hid  = gh[(ib + px) * 128 + 64 + cg];
            float z  = 1.f / (1.f + __expf(-gate));
            float gv = (hid >= 0.f) ? hid + 0.5f : 1.f / (1.f + __expf(-hid));
            h[i] = (1.f - z) * h[i] + z * gv;
            sh2[px][cg] = h[i];
        }
        __syncthreads();
        #pragma unroll
        for (int i = 0; i < 4; ++i) {
            int c2 = ocq * 4 + i;
            float v = sh2[opx][c2];
            out2[((size_t)(b * 64 + s) * 64 + c2) * 1024 + hw0 + opx] = v;
            if (s == 63)
                h2[(size_t)(b * 64 + c2) * 1024 + hw0 + opx] = v;
        }
        __syncthreads();
    }
}

// ---------------------------------------------------------------------------
// d_out floats: out2 [16777216] | h1 [262144] | h2 [262144]
// ws: gh (134 MB). Weight hi/lo buffers live in the h1/h2 output regions
// until consumed, then get overwritten by the real h1/h2 values.
// ---------------------------------------------------------------------------
extern "C" void kernel_launch(void* const* d_in, const int* in_sizes, int n_in,
                              void* d_out, int out_size, void* d_ws, size_t ws_size,
                              hipStream_t stream)
{
    const float* x  = (const float*)d_in[0];
    const float* w1 = (const float*)d_in[1];
    const float* b1 = (const float*)d_in[2];
    const float* w2 = (const float*)d_in[3];
    const float* b2 = (const float*)d_in[4];

    float* out  = (float*)d_out;
    float* gh   = (float*)d_ws;
    float* out1 = out;                          // NHWC scratch in out2 region
    float* h1   = out + 16777216;
    float* h2   = out + 17039360;

    uint16_t* w1hi = (uint16_t*)h1;             // 9*4096 halfs
    uint16_t* w1lo = w1hi + 36864;
    uint16_t* w2hi = (uint16_t*)h2;             // 18*4096 halfs
    uint16_t* w2lo = w2hi + 73728;

    repack_w<32><<<144, 256, 0, stream>>>(w1, w1hi, w1lo);
    repack_w<64><<<288, 256, 0, stream>>>(w2, w2hi, w2lo);

    conv_mfma<32, false><<<2048, 256, 0, stream>>>(x, w1hi, w1lo, b1, gh);
    scan_nhwc<<<1024, 256, 0, stream>>>(gh, out1, h1);
    conv_mfma<64, true><<<2048, 256, 0, stream>>>(out1, w2hi, w2lo, b2, gh);
    scan_nchw<<<256, 256, 0, stream>>>(gh, out, h2);
}

// Round 6
// 364.548 us; speedup vs baseline: 1.6253x; 1.6253x over previous
//
#include <hip/hip_runtime.h>
#include <math.h>
#include <stdint.h>

#define G_ZERO 0.5f

typedef _Float16 half8 __attribute__((ext_vector_type(8)));
typedef float f32x4 __attribute__((ext_vector_type(4)));

__device__ __host__ __forceinline__ int b_swz(int oc) {
    return (oc & 3) ^ ((oc >> 2) & 3);
}

// ---------------------------------------------------------------------------
// Weight repack (hi only, 1-pass f16): w fp32 [128][C][3][3] -> per-chunk
// swizzled f16 image matching the conv B LDS tile (chunk=(ky,kx,cs), K=32).
// dst halfword = tt*4096 + oc*32 + ((kloc>>3)^b_swz(oc))*8 + (kloc&7)
// ---------------------------------------------------------------------------
template<int C>
__global__ __launch_bounds__(256)
void repack_w(const float* __restrict__ w, uint16_t* __restrict__ whi)
{
    constexpr int nCs = C / 32;
    constexpr int nCh = 9 * nCs;
    int idx = blockIdx.x * 256 + threadIdx.x;
    if (idx >= nCh * 128 * 32) return;
    int kloc = idx & 31;
    int oc   = (idx >> 5) & 127;
    int tt   = idx >> 12;
    int kyx = tt / nCs, cs = tt % nCs;
    int ky = kyx / 3, kx = kyx % 3;
    int c = cs * 32 + kloc;
    float v = w[(size_t)oc * C * 9 + c * 9 + ky * 3 + kx];
    _Float16 hi = (_Float16)v;
    int dst = tt * 4096 + oc * 32 + (((kloc >> 3) ^ b_swz(oc)) << 3) + (kloc & 7);
    whi[dst] = __builtin_bit_cast(uint16_t, hi);
}

// ---------------------------------------------------------------------------
// Implicit-GEMM conv3x3, mfma_f32_16x16x32_f16, single pass (f16 inputs,
// fp32 accumulate). Block = 4 waves (2Mx2N), tile M=128 px x N=128 oc.
// A LDS: [6 rows][34 cols][8 x 16B slots] (pixel padded to 128B for both
//        convs), slot = (c>>3) ^ (col&7)  -> <=2-way bank conflicts.
// B LDS: one 8KB chunk buffer, cooperative stage + register prefetch;
//        cross-block barrier offset (4 blocks/CU) hides the stage stall.
// gh out: NHWC ((img*1024+y*32+x)*128 + oc), fp32 + bias.
// ---------------------------------------------------------------------------
template<int C, bool NHWC_IN>
__global__ __launch_bounds__(256, 4)
void conv_mfma(const float* __restrict__ in, const uint16_t* __restrict__ whi,
               const float* __restrict__ bias, float* __restrict__ gh)
{
    constexpr int nCs = C / 32;
    constexpr int nCh = 9 * nCs;
    constexpr int PIX_B = 128;                 // padded pixel stride
    constexpr int A_BYTES = 6 * 34 * PIX_B;    // 26112

    __shared__ char smem[A_BYTES + 8192];

    const int tid = threadIdx.x;
    const int l = tid & 63;
    const int wv = tid >> 6;
    const int wv_m = wv >> 1, wv_n = wv & 1;
    const int g16 = l >> 4;
    const int ln15 = l & 15;
    const int img = blockIdx.x >> 3;
    const int y0 = (blockIdx.x & 7) * 4;

    // ---- zero halo pixels (cols 0 and 33, full 128B each)
    for (int e = tid; e < 6 * 2 * 32; e += 256) {
        int pj = e >> 5;
        int j  = e & 31;
        int row = pj >> 1;
        int col = (pj & 1) ? 33 : 0;
        *(float*)(smem + (row * 34 + col) * PIX_B + j * 4) = 0.f;
    }
    // ---- stage A tile once: rows y0-1..y0+4, cols 1..32, f16
    for (int e = tid; e < C * 192; e += 256) {
        int c, x, y6;
        if constexpr (NHWC_IN) { c = e & (C - 1); int r2 = e >> 6; x = r2 & 31; y6 = r2 >> 5; }
        else                   { x = e & 31; int r2 = e >> 5; y6 = r2 % 6; c = r2 / 6; }
        int gy = y0 - 1 + y6;
        float v = 0.f;
        if ((unsigned)gy < 32u) {
            if constexpr (NHWC_IN) v = in[((size_t)img * 1024 + gy * 32 + x) * C + c];
            else                   v = in[((size_t)img * C + c) * 1024 + gy * 32 + x];
        }
        _Float16 hi = (_Float16)v;
        int col = x + 1;
        int slot = (c >> 3) ^ (col & 7);
        int addr = (y6 * 34 + col) * PIX_B + slot * 16 + (c & 7) * 2;
        *(uint16_t*)(smem + addr) = __builtin_bit_cast(uint16_t, hi);
    }

    // ---- per-lane precomputed addresses
    int acol[3][2];
    #pragma unroll
    for (int kx = 0; kx < 3; ++kx)
        #pragma unroll
        for (int m1 = 0; m1 < 2; ++m1) {
            int col = m1 * 16 + ln15 + kx;
            acol[kx][m1] = col * PIX_B + ((g16 ^ (col & 7)) << 4);
        }
    const int rowbase = wv_m * 2 * 34 * PIX_B;
    const int swz_l = (ln15 & 3) ^ ((ln15 >> 2) & 3);       // b_swz(oc), nf-invariant
    const int bbase = A_BYTES + (wv_n * 64 + ln15) * 64 + ((g16 ^ swz_l) << 4);
    char* const bb = smem + A_BYTES;

    f32x4 acc[4][4];
    #pragma unroll
    for (int mf = 0; mf < 4; ++mf)
        #pragma unroll
        for (int nf = 0; nf < 4; ++nf) acc[mf][nf] = (f32x4)0.f;

    // ---- prologue: stage B chunk 0
    int4 s0 = *(const int4*)((const char*)whi + tid * 16);
    int4 s1 = *(const int4*)((const char*)whi + 4096 + tid * 16);
    *(int4*)(bb + tid * 16) = s0;
    *(int4*)(bb + 4096 + tid * 16) = s1;
    __syncthreads();                   // A tile + B chunk 0 ready

    #pragma unroll
    for (int tt = 0; tt < nCh; ++tt) {
        if (tt + 1 < nCh) {            // prefetch next chunk to regs
            const char* p = (const char*)whi + (size_t)(tt + 1) * 8192;
            s0 = *(const int4*)(p + tid * 16);
            s1 = *(const int4*)(p + 4096 + tid * 16);
        }
        const int kyx = tt / nCs, cs = tt % nCs;
        const int ky = kyx / 3, kx = kyx % 3;

        half8 bh[4], ah[4];
        #pragma unroll
        for (int nf = 0; nf < 4; ++nf)
            bh[nf] = *(const half8*)(smem + bbase + nf * 1024);
        #pragma unroll
        for (int mf = 0; mf < 4; ++mf) {
            const int imm = ((mf >> 1) + ky) * 34 * PIX_B;  // compile-time
            ah[mf] = *(const half8*)(smem + rowbase + imm
                       + (acol[kx][mf & 1] ^ (cs << 6)));
        }
        #pragma unroll
        for (int mf = 0; mf < 4; ++mf)
            #pragma unroll
            for (int nf = 0; nf < 4; ++nf)
                acc[mf][nf] = __builtin_amdgcn_mfma_f32_16x16x32_f16(
                    ah[mf], bh[nf], acc[mf][nf], 0, 0, 0);

        __syncthreads();               // all waves done with chunk tt
        if (tt + 1 < nCh) {
            *(int4*)(bb + tid * 16) = s0;
            *(int4*)(bb + 4096 + tid * 16) = s1;
            __syncthreads();           // chunk tt+1 ready
        }
    }

    // ---- epilogue: C/D layout col(oc)=lane&15, row(px)=(lane>>4)*4+reg (m89)
    #pragma unroll
    for (int mf = 0; mf < 4; ++mf) {
        int pbase = wv_m * 64 + mf * 16 + g16 * 4;
        #pragma unroll
        for (int nf = 0; nf < 4; ++nf) {
            int oc = wv_n * 64 + nf * 16 + ln15;
            float bv = bias[oc];
            #pragma unroll
            for (int r = 0; r < 4; ++r) {
                int pp = pbase + r;
                int y = y0 + (pp >> 5), x = pp & 31;
                gh[((size_t)img * 1024 + y * 32 + x) * 128 + oc] = acc[mf][nf][r] + bv;
            }
        }
    }
}

// ---------------------------------------------------------------------------
// scan1: gh NHWC [img][1024][128] -> out1 NHWC [img][1024][64], h1 NCHW.
// ---------------------------------------------------------------------------
__global__ __launch_bounds__(256)
void scan_nhwc(const float* __restrict__ gh, float* __restrict__ out1,
               float* __restrict__ h1)
{
    int idx = blockIdx.x * 256 + threadIdx.x;   // 262144 total
    int cg = idx & 63;
    int hw = (idx >> 6) & 1023;
    int b  = idx >> 16;
    const float* gp = gh + ((size_t)(b * 64) * 1024 + hw) * 128 + cg;
    float* op = out1 + ((size_t)(b * 64) * 1024 + hw) * 64 + cg;
    float h = G_ZERO;
    for (int s = 0; s < 64; ++s) {
        float gate = gp[(size_t)s * 131072];
        float hid  = gp[(size_t)s * 131072 + 64];
        float z  = 1.f / (1.f + __expf(-gate));
        float gv = (hid >= 0.f) ? hid + 0.5f : 1.f / (1.f + __expf(-hid));
        h = (1.f - z) * h + z * gv;
        op[(size_t)s * 65536] = h;
    }
    h1[(size_t)(b * 64 + cg) * 1024 + hw] = h;
}

// ---------------------------------------------------------------------------
// scan2: gh NHWC -> out2 NCHW + h2 NCHW, LDS bounce for the transpose.
// ---------------------------------------------------------------------------
__global__ __launch_bounds__(256)
void scan_nchw(const float* __restrict__ gh, float* __restrict__ out2,
               float* __restrict__ h2)
{
    __shared__ float sh2[16][65];
    int tid = threadIdx.x;
    int b   = blockIdx.x >> 6;
    int hw0 = (blockIdx.x & 63) * 16;
    int cg = tid & 63, pq = tid >> 6;          // compute mapping (cg fastest)
    int opx = tid & 15, ocq = tid >> 4;        // store mapping (px fastest)
    float h[4] = {G_ZERO, G_ZERO, G_ZERO, G_ZERO};
    for (int s = 0; s < 64; ++s) {
        size_t ib = (size_t)(b * 64 + s) * 1024 + hw0;
        #pragma unroll
        for (int i = 0; i < 4; ++i) {
            int px = pq * 4 + i;
            float gate = gh[(ib + px) * 128 + cg];
            float hid  = gh[(ib + px) * 128 + 64 + cg];
            float z  = 1.f / (1.f + __expf(-gate));
            float gv = (hid >= 0.f) ? hid + 0.5f : 1.f / (1.f + __expf(-hid));
            h[i] = (1.f - z) * h[i] + z * gv;
            sh2[px][cg] = h[i];
        }
        __syncthreads();
        #pragma unroll
        for (int i = 0; i < 4; ++i) {
            int c2 = ocq * 4 + i;
            float v = sh2[opx][c2];
            out2[((size_t)(b * 64 + s) * 64 + c2) * 1024 + hw0 + opx] = v;
            if (s == 63)
                h2[(size_t)(b * 64 + c2) * 1024 + hw0 + opx] = v;
        }
        __syncthreads();
    }
}

// ---------------------------------------------------------------------------
// d_out floats: out2 [16777216] | h1 [262144] | h2 [262144]
// ws: gh (134 MB). Weight f16 buffers live in the h1/h2 output regions until
// consumed, then get overwritten by the real h1/h2 values.
// ---------------------------------------------------------------------------
extern "C" void kernel_launch(void* const* d_in, const int* in_sizes, int n_in,
                              void* d_out, int out_size, void* d_ws, size_t ws_size,
                              hipStream_t stream)
{
    const float* x  = (const float*)d_in[0];
    const float* w1 = (const float*)d_in[1];
    const float* b1 = (const float*)d_in[2];
    const float* w2 = (const float*)d_in[3];
    const float* b2 = (const float*)d_in[4];

    float* out  = (float*)d_out;
    float* gh   = (float*)d_ws;
    float* out1 = out;                          // NHWC scratch in out2 region
    float* h1   = out + 16777216;
    float* h2   = out + 17039360;

    uint16_t* w1hi = (uint16_t*)h1;             // 36864 halfs = 73 KB
    uint16_t* w2hi = (uint16_t*)h2;             // 73728 halfs = 147 KB

    repack_w<32><<<144, 256, 0, stream>>>(w1, w1hi);
    repack_w<64><<<288, 256, 0, stream>>>(w2, w2hi);

    conv_mfma<32, false><<<2048, 256, 0, stream>>>(x, w1hi, b1, gh);
    scan_nhwc<<<1024, 256, 0, stream>>>(gh, out1, h1);
    conv_mfma<64, true><<<2048, 256, 0, stream>>>(out1, w2hi, b2, gh);
    scan_nchw<<<256, 256, 0, stream>>>(gh, out, h2);
}